// Round 1
// baseline (2861.702 us; speedup 1.0000x reference)
//
#include <hip/hip_runtime.h>
#include <math.h>

// ---------------- kernels ----------------

__global__ void init_deg(float* deg, int n) {
    int i = blockIdx.x * blockDim.x + threadIdx.x;
    if (i < n) deg[i] = 1.0f;  // self-loop contributes 1 to in-degree
}

__global__ void count_deg(const int* __restrict__ dst, float* __restrict__ deg, int E) {
    int e = blockIdx.x * blockDim.x + threadIdx.x;
    if (e < E) atomicAdd(&deg[dst[e]], 1.0f);
}

__global__ void compute_dinv(float* deg, int n) {
    int i = blockIdx.x * blockDim.x + threadIdx.x;
    if (i < n) deg[i] = rsqrtf(deg[i]);  // deg >= 1 always (self-loops)
}

__global__ void compute_norm(const int* __restrict__ src, const int* __restrict__ dst,
                             const float* __restrict__ dinv, float* __restrict__ norm, int E) {
    int e = blockIdx.x * blockDim.x + threadIdx.x;
    if (e < E) norm[e] = dinv[src[e]] * dinv[dst[e]];
}

// out[n][j] = sum_k in[n][k] * W[k][j],  J = 64 fixed. One wave per row (row is
// wave-uniform -> scalar-friendly loads of the input row), W staged in LDS.
template <int K>
__global__ void gemm64(const float* __restrict__ in, const float* __restrict__ W,
                       float* __restrict__ out, int n_rows) {
    __shared__ float Ws[K * 64];
    int t = threadIdx.x;
    for (int i = t; i < K * 64; i += 256) Ws[i] = W[i];
    __syncthreads();
    int row = blockIdx.x * 4 + (t >> 6);
    int j = t & 63;
    if (row >= n_rows) return;
    const float* xr = in + (size_t)row * K;
    float acc = 0.0f;
#pragma unroll
    for (int k = 0; k < K; ++k) acc += xr[k] * Ws[k * 64 + j];
    out[(size_t)row * 64 + j] = acc;
}

// 16 threads per edge; each handles 4 consecutive output dims (float4 gather,
// 4 scalar atomic adds). agg must be pre-zeroed.
__global__ void scatter_edges(const int* __restrict__ src, const int* __restrict__ dst,
                              const float* __restrict__ norm, const float* __restrict__ xw,
                              float* __restrict__ agg, int E) {
    long long gid = (long long)blockIdx.x * blockDim.x + threadIdx.x;
    int e = (int)(gid >> 4);
    int q = (int)(gid & 15);
    if (e >= E) return;
    int s = src[e];
    int d = dst[e];
    float nm = norm[e];
    float4 v = *reinterpret_cast<const float4*>(xw + (size_t)s * 64 + q * 4);
    float* ap = agg + (size_t)d * 64 + q * 4;
    atomicAdd(ap + 0, v.x * nm);
    atomicAdd(ap + 1, v.y * nm);
    atomicAdd(ap + 2, v.z * nm);
    atomicAdd(ap + 3, v.w * nm);
}

// agg[i][j] = relu(agg[i][j] + xw[i][j]*dinv[i]^2 + b[j])   (self-loop + bias + relu)
__global__ void finish_layer(float* __restrict__ agg, const float* __restrict__ xw,
                             const float* __restrict__ dinv, const float* __restrict__ b, int n) {
    int gid = blockIdx.x * blockDim.x + threadIdx.x;
    if (gid >= n * 64) return;
    int i = gid >> 6;
    int j = gid & 63;
    float di = dinv[i];
    float v = agg[gid] + xw[gid] * di * di + b[j];
    agg[gid] = v > 0.0f ? v : 0.0f;
}

// column-wise sum over all nodes: g[j] += sum_i h[i][j]; g pre-zeroed.
__global__ void pool_sum(const float* __restrict__ h, float* __restrict__ g, int n) {
    int t = threadIdx.x;
    int j = t & 63;
    float acc = 0.0f;
    for (int r = blockIdx.x * 4 + (t >> 6); r < n; r += gridDim.x * 4)
        acc += h[(size_t)r * 64 + j];
    __shared__ float sdata[256];
    sdata[t] = acc;
    __syncthreads();
    if (t < 64) atomicAdd(&g[t], sdata[t] + sdata[t + 64] + sdata[t + 128] + sdata[t + 192]);
}

// logits = (g/n) @ Wfc + bfc ; out = log_softmax(logits).  Wfc is [64,5] row-major.
__global__ void final_head(const float* __restrict__ g, const float* __restrict__ Wfc,
                           const float* __restrict__ bfc, float* __restrict__ out, int n) {
    __shared__ float logits[5];
    int t = threadIdx.x;
    if (t < 5) {
        float acc = bfc[t];
        float invn = 1.0f / (float)n;
        for (int k = 0; k < 64; ++k) acc += (g[k] * invn) * Wfc[k * 5 + t];
        logits[t] = acc;
    }
    __syncthreads();
    if (t == 0) {
        float m = logits[0];
        for (int i = 1; i < 5; ++i) m = fmaxf(m, logits[i]);
        float s = 0.0f;
        for (int i = 0; i < 5; ++i) s += expf(logits[i] - m);
        float lse = m + logf(s);
        for (int i = 0; i < 5; ++i) out[i] = logits[i] - lse;
    }
}

// ---------------- launch ----------------

extern "C" void kernel_launch(void* const* d_in, const int* in_sizes, int n_in,
                              void* d_out, int out_size, void* d_ws, size_t ws_size,
                              hipStream_t stream) {
    const float* x   = (const float*)d_in[0];
    const int*   ei  = (const int*)d_in[1];
    const float* W1  = (const float*)d_in[2];
    const float* b1  = (const float*)d_in[3];
    const float* W2  = (const float*)d_in[4];
    const float* b2  = (const float*)d_in[5];
    const float* Wfc = (const float*)d_in[6];
    const float* bfc = (const float*)d_in[7];
    float* out = (float*)d_out;

    const int n = in_sizes[0] / 32;       // 100000
    const int E = in_sizes[1] / 2;        // 1600000
    const int* src = ei;
    const int* dst = ei + E;

    // workspace carve-up (all float)
    float* deg  = (float*)d_ws;                 // [n]   -> becomes dinv in place
    float* norm = deg + n;                      // [E]
    float* xw   = norm + E;                     // [n*64]
    float* agg  = xw + (size_t)n * 64;          // [n*64]
    float* g    = agg + (size_t)n * 64;         // [64]

    const int B = 256;

    // ---- graph normalization (shared by both layers) ----
    init_deg<<<(n + B - 1) / B, B, 0, stream>>>(deg, n);
    count_deg<<<(E + B - 1) / B, B, 0, stream>>>(dst, deg, E);
    compute_dinv<<<(n + B - 1) / B, B, 0, stream>>>(deg, n);
    compute_norm<<<(E + B - 1) / B, B, 0, stream>>>(src, dst, deg, norm, E);

    // ---- layer 1: xw = x @ W1 ; agg = scatter(norm * xw[src]) ; h1 = relu(agg + self + b1)
    gemm64<32><<<(n + 3) / 4, B, 0, stream>>>(x, W1, xw, n);
    hipMemsetAsync(agg, 0, (size_t)n * 64 * sizeof(float), stream);
    {
        long long tot = (long long)E * 16;
        scatter_edges<<<(int)((tot + B - 1) / B), B, 0, stream>>>(src, dst, norm, xw, agg, E);
    }
    finish_layer<<<(n * 64 + B - 1) / B, B, 0, stream>>>(agg, xw, deg, b1, n);

    // ---- layer 2: xw = h1 @ W2 ; re-aggregate into agg (zeroed after gemm reads h1)
    gemm64<64><<<(n + 3) / 4, B, 0, stream>>>(agg, W2, xw, n);
    hipMemsetAsync(agg, 0, (size_t)n * 64 * sizeof(float), stream);
    {
        long long tot = (long long)E * 16;
        scatter_edges<<<(int)((tot + B - 1) / B), B, 0, stream>>>(src, dst, norm, xw, agg, E);
    }
    finish_layer<<<(n * 64 + B - 1) / B, B, 0, stream>>>(agg, xw, deg, b2, n);

    // ---- mean pool + FC + log_softmax ----
    hipMemsetAsync(g, 0, 64 * sizeof(float), stream);
    pool_sum<<<256, B, 0, stream>>>(agg, g, n);
    final_head<<<1, 64, 0, stream>>>(g, Wfc, bfc, out, n);
}

// Round 2
// 418.671 us; speedup vs baseline: 6.8352x; 6.8352x over previous
//
#include <hip/hip_runtime.h>
#include <math.h>

// ---------------- graph build ----------------

__global__ void count_deg_int(const int* __restrict__ dst, int* __restrict__ cnt, int E) {
    int e = blockIdx.x * blockDim.x + threadIdx.x;
    if (e < E) atomicAdd(&cnt[dst[e]], 1);
}

__global__ void compute_dinv(const int* __restrict__ cnt, float* __restrict__ dinv, int n) {
    int i = blockIdx.x * blockDim.x + threadIdx.x;
    if (i < n) dinv[i] = rsqrtf((float)(cnt[i] + 1));  // +1 self-loop
}

// 2-level exclusive scan over cnt[n]: block of 256 threads x 4 items = 1024/block
__global__ void scan_blocks(const int* __restrict__ cnt, int* __restrict__ excl,
                            int* __restrict__ partials, int n) {
    __shared__ int lds[256];
    int t = threadIdx.x;
    int base = blockIdx.x * 1024 + t * 4;
    int v0 = (base + 0 < n) ? cnt[base + 0] : 0;
    int v1 = (base + 1 < n) ? cnt[base + 1] : 0;
    int v2 = (base + 2 < n) ? cnt[base + 2] : 0;
    int v3 = (base + 3 < n) ? cnt[base + 3] : 0;
    int s = v0 + v1 + v2 + v3;
    lds[t] = s;
    __syncthreads();
    for (int off = 1; off < 256; off <<= 1) {
        int y = (t >= off) ? lds[t - off] : 0;
        __syncthreads();
        lds[t] += y;
        __syncthreads();
    }
    int eb = lds[t] - s;  // exclusive base for this thread's chunk
    if (base + 0 < n) excl[base + 0] = eb;
    if (base + 1 < n) excl[base + 1] = eb + v0;
    if (base + 2 < n) excl[base + 2] = eb + v0 + v1;
    if (base + 3 < n) excl[base + 3] = eb + v0 + v1 + v2;
    if (t == 255) partials[blockIdx.x] = lds[255];
}

__global__ void scan_partials(int* __restrict__ partials, int nparts) {
    __shared__ int lds[256];
    int t = threadIdx.x;
    int v = (t < nparts) ? partials[t] : 0;
    lds[t] = v;
    __syncthreads();
    for (int off = 1; off < 256; off <<= 1) {
        int y = (t >= off) ? lds[t - off] : 0;
        __syncthreads();
        lds[t] += y;
        __syncthreads();
    }
    if (t < nparts) partials[t] = lds[t] - v;  // exclusive
}

// rowptr[i] = excl[i] + partials[block]; cursor[i] = rowptr[i]
__global__ void add_copy(int* __restrict__ rowptr, const int* __restrict__ partials,
                         int* __restrict__ cursor, int n) {
    int i = blockIdx.x * blockDim.x + threadIdx.x;
    if (i < n) {
        int r = rowptr[i] + partials[i >> 10];
        rowptr[i] = r;
        cursor[i] = r;
    }
}

__global__ void fill_csr(const int* __restrict__ src, const int* __restrict__ dst,
                         int* __restrict__ cursor, int* __restrict__ csr_src, int E) {
    int e = blockIdx.x * blockDim.x + threadIdx.x;
    if (e < E) {
        int pos = atomicAdd(&cursor[dst[e]], 1);
        csr_src[pos] = src[e];
    }
}

// ---------------- aggregation (gather, no atomics) ----------------
// out[d][j] = dinv[d]^2 * feat[d][j] + sum_k dinv[s_k]*dinv[d] * feat[s_k][j]

template <int D, int NPB>  // dims per row, nodes per block (D*NPB == 256)
__global__ void agg_gather(const int* __restrict__ rowptr, const int* __restrict__ rowend,
                           const int* __restrict__ csr_src, const float* __restrict__ dinv,
                           const float* __restrict__ feat, float* __restrict__ out, int n) {
    int node = blockIdx.x * NPB + (threadIdx.x / D);
    int j = threadIdx.x % D;
    if (node >= n) return;
    int k = rowptr[node];
    int end = rowend[node];
    float di = dinv[node];
    float acc = feat[(size_t)node * D + j] * di * di;
    for (; k + 4 <= end; k += 4) {
        int s0 = csr_src[k], s1 = csr_src[k + 1], s2 = csr_src[k + 2], s3 = csr_src[k + 3];
        float w0 = dinv[s0] * di, w1 = dinv[s1] * di, w2 = dinv[s2] * di, w3 = dinv[s3] * di;
        float v0 = feat[(size_t)s0 * D + j];
        float v1 = feat[(size_t)s1 * D + j];
        float v2 = feat[(size_t)s2 * D + j];
        float v3 = feat[(size_t)s3 * D + j];
        acc += v0 * w0 + v1 * w1 + v2 * w2 + v3 * w3;
    }
    for (; k < end; ++k) {
        int s = csr_src[k];
        acc += feat[(size_t)s * D + j] * dinv[s] * di;
    }
    out[(size_t)node * D + j] = acc;
}

// ---------------- dense layers ----------------

// out[row][j] = relu(bias[j] + sum_k in[row][k]*W[k][j]), J=64. One wave per row.
template <int K>
__global__ void gemm_bias_relu(const float* __restrict__ in, const float* __restrict__ W,
                               const float* __restrict__ bias, float* __restrict__ out, int n) {
    __shared__ float Ws[K * 64];
    __shared__ float bs[64];
    int t = threadIdx.x;
    for (int i = t; i < K * 64; i += 256) Ws[i] = W[i];
    if (t < 64) bs[t] = bias[t];
    __syncthreads();
    int row = blockIdx.x * 4 + (t >> 6);
    int j = t & 63;
    if (row >= n) return;
    const float* xr = in + (size_t)row * K;
    float acc = bs[j];
#pragma unroll
    for (int k = 0; k < K; ++k) acc += xr[k] * Ws[k * 64 + j];
    out[(size_t)row * 64 + j] = fmaxf(acc, 0.0f);
}

// fused: h2 = relu(in@W2 + b2); g[j] += column sums of h2 (h2 never stored)
__global__ void gemm_relu_pool(const float* __restrict__ in, const float* __restrict__ W,
                               const float* __restrict__ bias, float* __restrict__ g, int n) {
    __shared__ float Ws[64 * 64];
    int t = threadIdx.x;
    for (int i = t; i < 64 * 64; i += 256) Ws[i] = W[i];
    __syncthreads();
    int j = t & 63;
    float b = bias[j];
    float pool = 0.0f;
    for (int row = blockIdx.x * 4 + (t >> 6); row < n; row += gridDim.x * 4) {
        const float* xr = in + (size_t)row * 64;
        float acc = b;
#pragma unroll
        for (int k = 0; k < 64; ++k) acc += xr[k] * Ws[k * 64 + j];
        pool += fmaxf(acc, 0.0f);
    }
    __shared__ float sd[256];
    sd[t] = pool;
    __syncthreads();
    if (t < 64) atomicAdd(&g[t], sd[t] + sd[t + 64] + sd[t + 128] + sd[t + 192]);
}

__global__ void final_head(const float* __restrict__ g, const float* __restrict__ Wfc,
                           const float* __restrict__ bfc, float* __restrict__ out, int n) {
    __shared__ float logits[5];
    int t = threadIdx.x;
    if (t < 5) {
        float acc = bfc[t];
        float invn = 1.0f / (float)n;
        for (int k = 0; k < 64; ++k) acc += (g[k] * invn) * Wfc[k * 5 + t];
        logits[t] = acc;
    }
    __syncthreads();
    if (t == 0) {
        float m = logits[0];
        for (int i = 1; i < 5; ++i) m = fmaxf(m, logits[i]);
        float s = 0.0f;
        for (int i = 0; i < 5; ++i) s += expf(logits[i] - m);
        float lse = m + logf(s);
        for (int i = 0; i < 5; ++i) out[i] = logits[i] - lse;
    }
}

// ---------------- launch ----------------

extern "C" void kernel_launch(void* const* d_in, const int* in_sizes, int n_in,
                              void* d_out, int out_size, void* d_ws, size_t ws_size,
                              hipStream_t stream) {
    const float* x   = (const float*)d_in[0];
    const int*   ei  = (const int*)d_in[1];
    const float* W1  = (const float*)d_in[2];
    const float* b1  = (const float*)d_in[3];
    const float* W2  = (const float*)d_in[4];
    const float* b2  = (const float*)d_in[5];
    const float* Wfc = (const float*)d_in[6];
    const float* bfc = (const float*)d_in[7];
    float* out = (float*)d_out;

    const int n = in_sizes[0] / 32;   // 100000
    const int E = in_sizes[1] / 2;    // 1600000
    const int* src = ei;
    const int* dst = ei + E;

    // workspace carve-up
    int*   cnt      = (int*)d_ws;                    // [n] -> reused as cursor
    int*   rowptr   = cnt + n;                       // [n]
    int*   partials = rowptr + n;                    // [256]
    int*   csr_src  = partials + 256;                // [E]
    float* dinv     = (float*)(csr_src + E);         // [n]
    float* aggbuf   = dinv + n;                      // [n*64] (layer1 uses first n*32)
    float* h1       = aggbuf + (size_t)n * 64;       // [n*64]
    float* g        = h1 + (size_t)n * 64;           // [64]
    int*   cursor   = cnt;                           // alias (cnt dead after scan)

    const int B = 256;
    const int nblocks_scan = (n + 1023) / 1024;

    // ---- build CSR + norms ----
    hipMemsetAsync(cnt, 0, (size_t)n * sizeof(int), stream);
    count_deg_int<<<(E + B - 1) / B, B, 0, stream>>>(dst, cnt, E);
    compute_dinv<<<(n + B - 1) / B, B, 0, stream>>>(cnt, dinv, n);
    scan_blocks<<<nblocks_scan, B, 0, stream>>>(cnt, rowptr, partials, n);
    scan_partials<<<1, B, 0, stream>>>(partials, nblocks_scan);
    add_copy<<<(n + B - 1) / B, B, 0, stream>>>(rowptr, partials, cursor, n);
    fill_csr<<<(E + B - 1) / B, B, 0, stream>>>(src, dst, cursor, csr_src, E);
    // after fill, cursor[d] == rowend[d]

    // ---- layer 1: agg(x) [n,32] then gemm+bias+relu -> h1 [n,64] ----
    agg_gather<32, 8><<<(n + 7) / 8, B, 0, stream>>>(rowptr, cursor, csr_src, dinv, x, aggbuf, n);
    gemm_bias_relu<32><<<(n + 3) / 4, B, 0, stream>>>(aggbuf, W1, b1, h1, n);

    // ---- layer 2: agg(h1) [n,64] then fused gemm+relu+pool ----
    agg_gather<64, 4><<<(n + 3) / 4, B, 0, stream>>>(rowptr, cursor, csr_src, dinv, h1, aggbuf, n);
    hipMemsetAsync(g, 0, 64 * sizeof(float), stream);
    gemm_relu_pool<<<1024, B, 0, stream>>>(aggbuf, W2, b2, g, n);

    // ---- head ----
    final_head<<<1, 64, 0, stream>>>(g, Wfc, bfc, out, n);
}